// Round 1
// baseline (321.879 us; speedup 1.0000x reference)
//
#include <hip/hip_runtime.h>
#include <math.h>

typedef __attribute__((ext_vector_type(8))) short short8;
typedef __attribute__((ext_vector_type(4))) float f32x4;

#define D 160
#define NTOK (256*512)   // 131072 rows
#define RW 16            // rows per block == one wave

__device__ __forceinline__ short f2bf(float f) {
  union { float f; unsigned u; } v; v.f = f;
  return (short)((v.u + 0x8000u) >> 16);   // round-half-up (=RNE except exact ties)
}

// bf16 eta tile: 16 rows x 160 cols, row stride 192 shorts (24 granules of 16B).
// XOR the low 3 bits of the 16B-granule index with row&7: a wave's b128 reads
// (16 rows at one col) spread over 8 distinct 4-bank slots -> 2-way max (free).
__device__ __forceinline__ int eidx(int row, int col) {
  int g = col >> 3;
  g = (g & ~7) | ((g ^ (row & 7)) & 7);
  return row * 192 + (g << 3) + (col & 7);
}
// f32 glu tile: 16 rows x 160 cols, row stride 160 floats (40 granules of 16B).
__device__ __forceinline__ int gidx(int row, int col) {
  int g = col >> 2;
  g = (g & ~7) | ((g ^ (row & 7)) & 7);
  return row * 160 + (g << 2) + (col & 3);
}

// Pack weights to bf16 in MFMA B-FRAGMENT ORDER (unchanged):
//   frag f = ks*10 + nt;  element (f, lane, j) = W[n][k],
//   n = nt*16 + (lane&15), k = ks*32 + (lane>>4)*8 + j.
__global__ __launch_bounds__(256) void prep_kernel(
    const float* __restrict__ W2, const float* __restrict__ W3,
    const float* __restrict__ W1, const float* __restrict__ W4,
    const float* __restrict__ W5, short* __restrict__ ws) {
  int i = blockIdx.x * 256 + threadIdx.x;
  if (i >= 128000) return;
  if (i < 51200) {
    int f = i >> 9, r = i & 511;
    int lane = r >> 3, j = r & 7;
    int ks = f / 10, nt = f % 10;
    int n = nt * 16 + (lane & 15);
    int k = ks * 32 + (lane >> 4) * 8 + j;
    float v = (k < 160) ? W2[n * 160 + k] : W3[n * 160 + (k - 160)];
    ws[i] = f2bf(v);
  } else {
    int idx = i - 51200;
    int which = idx / 25600;      // 0=W1, 1=W4, 2=W5
    int e = idx % 25600;
    int f = e >> 9, r = e & 511;
    int lane = r >> 3, j = r & 7;
    int ks = f / 10, nt = f % 10;
    int n = nt * 16 + (lane & 15);
    int k = ks * 32 + (lane >> 4) * 8 + j;
    const float* W = (which == 0) ? W1 : (which == 1) ? W4 : W5;
    ws[i] = f2bf(W[n * 160 + k]);
  }
}

union LdsBuf {
  short e[RW * 192];   // 6144 B  (eta2, then eta1 in place)
  float g[RW * 160];   // 10240 B (glu, epilogue only; overwrites dead eta1)
};

// One wave per block, 16 rows. No barriers anywhere: all LDS traffic is
// wave-internal (DS ops from one wave execute in order).
//   phase1: A-fragments of [x|c] loaded DIRECTLY from global (f32->bf16 in reg)
//   phase2: eta1 overwrites eta2 in LDS (all reads precede writes in program order)
//   phase3: GLU -> f32 LDS tile; LN pass re-reads it vectorized + f32x4 x reload
__global__ __launch_bounds__(64, 4) void grn_main(
    const float* __restrict__ x, const float* __restrict__ c,
    const short* __restrict__ wcatf, const short* __restrict__ w1f,
    const short* __restrict__ w4f, const short* __restrict__ w5f,
    const float* __restrict__ b2, const float* __restrict__ b1,
    const float* __restrict__ b4, const float* __restrict__ b5,
    const float* __restrict__ gamma, const float* __restrict__ beta,
    float* __restrict__ out) {
  __shared__ __align__(16) LdsBuf L;

  const int lane = threadIdx.x;     // 0..63
  const int lr   = lane & 15;
  const int quad = lane >> 4;
  const int rowbase = blockIdx.x * RW;

  const float* px = x + (size_t)(rowbase + lr) * D + quad * 8;
  const float* pc = c + (size_t)(rowbase + lr) * D + quad * 8;

  // ---------------- phase 1: eta2 = ELU([x|c] @ wcat^T + b2) ----------------
  {
    f32x4 acc[10];
#pragma unroll
    for (int nt = 0; nt < 10; ++nt) acc[nt] = (f32x4){0.f, 0.f, 0.f, 0.f};
    const short* wp = wcatf + lane * 8;
#pragma unroll
    for (int ks = 0; ks < 10; ++ks) {
      const float* ap = (ks < 5) ? (px + ks * 32) : (pc + (ks - 5) * 32);
      f32x4 lo = *(const f32x4*)ap;
      f32x4 hi = *(const f32x4*)(ap + 4);
      short8 af;
#pragma unroll
      for (int j = 0; j < 4; ++j) { af[j] = f2bf(lo[j]); af[4 + j] = f2bf(hi[j]); }
#pragma unroll
      for (int nt = 0; nt < 10; ++nt) {
        short8 b = *(const short8*)(wp + ((ks * 10 + nt) << 9));
        acc[nt] = __builtin_amdgcn_mfma_f32_16x16x32_bf16(af, b, acc[nt], 0, 0, 0);
      }
    }
#pragma unroll
    for (int nt = 0; nt < 10; ++nt) {
      float bias = b2[nt * 16 + lr];
#pragma unroll
      for (int r = 0; r < 4; ++r) {
        float v = acc[nt][r] + bias;
        v = v > 0.f ? v : (__expf(v) - 1.f);   // ELU
        L.e[eidx(quad * 4 + r, nt * 16 + lr)] = f2bf(v);
      }
    }
  }

  // ---------------- phase 2: eta1 = eta2 @ W1^T + b1 (in-place) -------------
  {
    f32x4 acc[10];
#pragma unroll
    for (int nt = 0; nt < 10; ++nt) acc[nt] = (f32x4){0.f, 0.f, 0.f, 0.f};
    const short* wp = w1f + lane * 8;
#pragma unroll
    for (int ks = 0; ks < 5; ++ks) {
      short8 af = *(const short8*)&L.e[eidx(lr, ks * 32 + quad * 8)];
#pragma unroll
      for (int nt = 0; nt < 10; ++nt) {
        short8 b = *(const short8*)(wp + ((ks * 10 + nt) << 9));
        acc[nt] = __builtin_amdgcn_mfma_f32_16x16x32_bf16(af, b, acc[nt], 0, 0, 0);
      }
    }
#pragma unroll
    for (int nt = 0; nt < 10; ++nt) {
      float bias = b1[nt * 16 + lr];
#pragma unroll
      for (int r = 0; r < 4; ++r) {
        float v = acc[nt][r] + bias;
        L.e[eidx(quad * 4 + r, nt * 16 + lr)] = f2bf(v);
      }
    }
  }

  // ---------------- phase 3: GLU -> f32 LDS tile ----------------------------
  {
    f32x4 accg[10], accv[10];
#pragma unroll
    for (int nt = 0; nt < 10; ++nt) {
      accg[nt] = (f32x4){0.f, 0.f, 0.f, 0.f};
      accv[nt] = (f32x4){0.f, 0.f, 0.f, 0.f};
    }
    const short* wp4 = w4f + lane * 8;
    const short* wp5 = w5f + lane * 8;
#pragma unroll
    for (int ks = 0; ks < 5; ++ks) {
      short8 af = *(const short8*)&L.e[eidx(lr, ks * 32 + quad * 8)];
#pragma unroll
      for (int nt = 0; nt < 10; ++nt) {
        short8 bg = *(const short8*)(wp4 + ((ks * 10 + nt) << 9));
        short8 bv = *(const short8*)(wp5 + ((ks * 10 + nt) << 9));
        accg[nt] = __builtin_amdgcn_mfma_f32_16x16x32_bf16(af, bg, accg[nt], 0, 0, 0);
        accv[nt] = __builtin_amdgcn_mfma_f32_16x16x32_bf16(af, bv, accv[nt], 0, 0, 0);
      }
    }
#pragma unroll
    for (int nt = 0; nt < 10; ++nt) {
      float bgs = b4[nt * 16 + lr];
      float bvs = b5[nt * 16 + lr];
#pragma unroll
      for (int r = 0; r < 4; ++r) {
        float g = accg[nt][r] + bgs;
        float v = accv[nt][r] + bvs;
        // glu in f32: writes depend on all eta1 reads (via MFMA), so the
        // union overwrite is ordered by data dependence.
        L.g[gidx(quad * 4 + r, nt * 16 + lr)] = v * __builtin_amdgcn_rcpf(1.f + __expf(-g));
      }
    }
  }

  // ---------------- LN pass: y = x + glu, normalize, store (vectorized) -----
  {
    const int lrow = lane >> 2;       // 0..15
    const int seg  = lane & 3;        // 40-col segment
    const float* xr = x + (size_t)(rowbase + lrow) * D + seg * 40;
    f32x4 yv[10];
    float sum = 0.f, ssq = 0.f;
#pragma unroll
    for (int i = 0; i < 10; ++i) {
      f32x4 gl = *(const f32x4*)&L.g[gidx(lrow, seg * 40 + i * 4)];
      f32x4 xv = *(const f32x4*)(xr + i * 4);
      f32x4 y;
#pragma unroll
      for (int j = 0; j < 4; ++j) {
        y[j] = xv[j] + gl[j];
        sum += y[j];
        ssq += y[j] * y[j];
      }
      yv[i] = y;
    }
    // combine the 4 lanes that share a row (lane bits 0..1)
    sum += __shfl_xor(sum, 1, 64); ssq += __shfl_xor(ssq, 1, 64);
    sum += __shfl_xor(sum, 2, 64); ssq += __shfl_xor(ssq, 2, 64);
    float mean = sum * (1.f / 160.f);
    float var  = ssq * (1.f / 160.f) - mean * mean;
    float rstd = __builtin_amdgcn_rsqf(var + 1e-5f);

    const float* gp = gamma + seg * 40;
    const float* bp = beta  + seg * 40;
    float* op = out + (size_t)(rowbase + lrow) * D + seg * 40;
#pragma unroll
    for (int i = 0; i < 10; ++i) {
      f32x4 ga = *(const f32x4*)(gp + i * 4);
      f32x4 be = *(const f32x4*)(bp + i * 4);
      f32x4 o;
#pragma unroll
      for (int j = 0; j < 4; ++j)
        o[j] = (yv[i][j] - mean) * rstd * ga[j] + be[j];
      *(f32x4*)(op + i * 4) = o;
    }
  }
}

extern "C" void kernel_launch(void* const* d_in, const int* in_sizes, int n_in,
                              void* d_out, int out_size, void* d_ws, size_t ws_size,
                              hipStream_t stream) {
  const float* x     = (const float*)d_in[0];
  const float* c     = (const float*)d_in[1];
  const float* W2    = (const float*)d_in[2];
  const float* b2    = (const float*)d_in[3];
  const float* W3    = (const float*)d_in[4];
  const float* W1    = (const float*)d_in[5];
  const float* b1    = (const float*)d_in[6];
  const float* W4    = (const float*)d_in[7];
  const float* b4    = (const float*)d_in[8];
  const float* W5    = (const float*)d_in[9];
  const float* b5    = (const float*)d_in[10];
  const float* gamma = (const float*)d_in[11];
  const float* beta  = (const float*)d_in[12];

  short* ws = (short*)d_ws;   // 256000 B; re-packed every launch
  prep_kernel<<<500, 256, 0, stream>>>(W2, W3, W1, W4, W5, ws);

  const short* wcatf = ws;
  const short* w1f   = ws + 51200;
  const short* w4f   = w1f + 25600;
  const short* w5f   = w4f + 25600;

  grn_main<<<NTOK / RW, 64, 0, stream>>>(x, c, wcatf, w1f, w4f, w5f,
                                         b2, b1, b4, b5, gamma, beta,
                                         (float*)d_out);
}

// Round 2
// 321.594 us; speedup vs baseline: 1.0009x; 1.0009x over previous
//
#include <hip/hip_runtime.h>
#include <math.h>

typedef __attribute__((ext_vector_type(8))) short short8;
typedef __attribute__((ext_vector_type(4))) float f32x4;

#define D 160
#define NTOK (256*512)   // 131072 rows
#define RW 16            // rows per block == one wave

__device__ __forceinline__ short f2bf(float f) {
  union { float f; unsigned u; } v; v.f = f;
  return (short)((v.u + 0x8000u) >> 16);   // round-half-up (=RNE except exact ties)
}

// bf16 eta tile: 16 rows x 160 cols, row stride 192 shorts (24 granules of 16B).
// XOR low 3 bits of granule index with row&7 -> 2-way max bank aliasing (free).
__device__ __forceinline__ int eidx(int row, int col) {
  int g = col >> 3;
  g = (g & ~7) | ((g ^ (row & 7)) & 7);
  return row * 192 + (g << 3) + (col & 7);
}
// f32 glu tile: 16 rows x 160 cols.
__device__ __forceinline__ int gidx(int row, int col) {
  int g = col >> 2;
  g = (g & ~7) | ((g ^ (row & 7)) & 7);
  return row * 160 + (g << 2) + (col & 3);
}

// Pack weights to bf16 in MFMA B-FRAGMENT ORDER (unchanged):
//   frag f = ks*10 + nt;  element (f, lane, j) = W[n][k],
//   n = nt*16 + (lane&15), k = ks*32 + (lane>>4)*8 + j.
__global__ __launch_bounds__(256) void prep_kernel(
    const float* __restrict__ W2, const float* __restrict__ W3,
    const float* __restrict__ W1, const float* __restrict__ W4,
    const float* __restrict__ W5, short* __restrict__ ws) {
  int i = blockIdx.x * 256 + threadIdx.x;
  if (i >= 128000) return;
  if (i < 51200) {
    int f = i >> 9, r = i & 511;
    int lane = r >> 3, j = r & 7;
    int ks = f / 10, nt = f % 10;
    int n = nt * 16 + (lane & 15);
    int k = ks * 32 + (lane >> 4) * 8 + j;
    float v = (k < 160) ? W2[n * 160 + k] : W3[n * 160 + (k - 160)];
    ws[i] = f2bf(v);
  } else {
    int idx = i - 51200;
    int which = idx / 25600;      // 0=W1, 1=W4, 2=W5
    int e = idx % 25600;
    int f = e >> 9, r = e & 511;
    int lane = r >> 3, j = r & 7;
    int ks = f / 10, nt = f % 10;
    int n = nt * 16 + (lane & 15);
    int k = ks * 32 + (lane >> 4) * 8 + j;
    const float* W = (which == 0) ? W1 : (which == 1) ? W4 : W5;
    ws[i] = f2bf(W[n * 160 + k]);
  }
}

union LdsBuf {
  short e[RW * 192];   // 6144 B  (eta2, then eta1 in place)
  float g[RW * 160];   // 10240 B (glu, epilogue only; overwrites dead eta)
};

// One wave per block, 16 rows, no barriers. This round: DEEP PREFETCH.
// launch_bounds(64,2) gives the allocator a 256-VGPR budget so load batches
// stay live: all 20 x/c loads issued up front, B fragments double-buffered,
// next phase's first B group issued before the current epilogue, and the
// LN-pass x reload issued under the GLU epilogue.
__global__ __launch_bounds__(64, 2) void grn_main(
    const float* __restrict__ x, const float* __restrict__ c,
    const short* __restrict__ wcatf, const short* __restrict__ w1f,
    const short* __restrict__ w4f, const short* __restrict__ w5f,
    const float* __restrict__ b2, const float* __restrict__ b1,
    const float* __restrict__ b4, const float* __restrict__ b5,
    const float* __restrict__ gamma, const float* __restrict__ beta,
    float* __restrict__ out) {
  __shared__ __align__(16) LdsBuf L;

  const int lane = threadIdx.x;     // 0..63
  const int lr   = lane & 15;
  const int quad = lane >> 4;
  const int rowbase = blockIdx.x * RW;

  const float* px = x + (size_t)(rowbase + lr) * D + quad * 8;
  const float* pc = c + (size_t)(rowbase + lr) * D + quad * 8;
  const short* wp  = wcatf + lane * 8;
  const short* wp1 = w1f + lane * 8;
  const short* wp4 = w4f + lane * 8;
  const short* wp5 = w5f + lane * 8;

  // ---------------- phase 1: eta2 = ELU([x|c] @ wcat^T + b2) ----------------
  short8 pf[10];   // cross-phase B prefetch carrier
  {
    f32x4 acc[10];
#pragma unroll
    for (int nt = 0; nt < 10; ++nt) acc[nt] = (f32x4){0.f, 0.f, 0.f, 0.f};

    // issue first B group, then ALL 20 A loads (stay in flight together)
    short8 bf[10], bn[10];
#pragma unroll
    for (int nt = 0; nt < 10; ++nt) bf[nt] = *(const short8*)(wp + (nt << 9));
    f32x4 alo[10], ahi[10];
#pragma unroll
    for (int i = 0; i < 10; ++i) {
      const float* ap = (i < 5) ? (px + i * 32) : (pc + (i - 5) * 32);
      alo[i] = *(const f32x4*)ap;
      ahi[i] = *(const f32x4*)(ap + 4);
    }
    float bias2[10];
#pragma unroll
    for (int nt = 0; nt < 10; ++nt) bias2[nt] = b2[nt * 16 + lr];

#pragma unroll
    for (int ks = 0; ks < 10; ++ks) {
      short8 af;
#pragma unroll
      for (int j = 0; j < 4; ++j) { af[j] = f2bf(alo[ks][j]); af[4 + j] = f2bf(ahi[ks][j]); }
#pragma unroll
      for (int nt = 0; nt < 10; ++nt)
        if (ks < 9) bn[nt] = *(const short8*)(wp + (((ks + 1) * 10 + nt) << 9));
#pragma unroll
      for (int nt = 0; nt < 10; ++nt)
        acc[nt] = __builtin_amdgcn_mfma_f32_16x16x32_bf16(af, bf[nt], acc[nt], 0, 0, 0);
#pragma unroll
      for (int nt = 0; nt < 10; ++nt)
        if (ks < 9) bf[nt] = bn[nt];
    }

    // prefetch phase-2 first B group under the ELU epilogue
#pragma unroll
    for (int nt = 0; nt < 10; ++nt) pf[nt] = *(const short8*)(wp1 + (nt << 9));

#pragma unroll
    for (int nt = 0; nt < 10; ++nt) {
#pragma unroll
      for (int r = 0; r < 4; ++r) {
        float v = acc[nt][r] + bias2[nt];
        v = v > 0.f ? v : (__expf(v) - 1.f);   // ELU
        L.e[eidx(quad * 4 + r, nt * 16 + lr)] = f2bf(v);
      }
    }
  }

  // ---------------- phase 2: eta1 = eta2 @ W1^T + b1 (in-place) -------------
  {
    f32x4 acc[10];
#pragma unroll
    for (int nt = 0; nt < 10; ++nt) acc[nt] = (f32x4){0.f, 0.f, 0.f, 0.f};
    float bias1[10];
#pragma unroll
    for (int nt = 0; nt < 10; ++nt) bias1[nt] = b1[nt * 16 + lr];

    short8 bf[10], bn[10];
#pragma unroll
    for (int nt = 0; nt < 10; ++nt) bf[nt] = pf[nt];

    short8 af = *(const short8*)&L.e[eidx(lr, quad * 8)];
    short8 afn;
#pragma unroll
    for (int ks = 0; ks < 5; ++ks) {
      if (ks < 4) afn = *(const short8*)&L.e[eidx(lr, (ks + 1) * 32 + quad * 8)];
#pragma unroll
      for (int nt = 0; nt < 10; ++nt)
        if (ks < 4) bn[nt] = *(const short8*)(wp1 + (((ks + 1) * 10 + nt) << 9));
#pragma unroll
      for (int nt = 0; nt < 10; ++nt)
        acc[nt] = __builtin_amdgcn_mfma_f32_16x16x32_bf16(af, bf[nt], acc[nt], 0, 0, 0);
#pragma unroll
      for (int nt = 0; nt < 10; ++nt)
        if (ks < 4) bf[nt] = bn[nt];
      if (ks < 4) af = afn;
    }

    // prefetch phase-3 first gate group under the eta1 epilogue
#pragma unroll
    for (int nt = 0; nt < 10; ++nt) pf[nt] = *(const short8*)(wp4 + (nt << 9));

#pragma unroll
    for (int nt = 0; nt < 10; ++nt) {
#pragma unroll
      for (int r = 0; r < 4; ++r) {
        float v = acc[nt][r] + bias1[nt];
        L.e[eidx(quad * 4 + r, nt * 16 + lr)] = f2bf(v);
      }
    }
  }

  // ---------------- phase 3: GLU -> f32 LDS tile ----------------------------
  {
    f32x4 accg[10], accv[10];
#pragma unroll
    for (int nt = 0; nt < 10; ++nt) {
      accg[nt] = (f32x4){0.f, 0.f, 0.f, 0.f};
      accv[nt] = (f32x4){0.f, 0.f, 0.f, 0.f};
    }
    float bias4[10], bias5[10];
#pragma unroll
    for (int nt = 0; nt < 10; ++nt) { bias4[nt] = b4[nt * 16 + lr]; bias5[nt] = b5[nt * 16 + lr]; }

    short8 bg[10], bgn[10], bv[10];
#pragma unroll
    for (int nt = 0; nt < 10; ++nt) bg[nt] = pf[nt];

    short8 af = *(const short8*)&L.e[eidx(lr, quad * 8)];
    short8 afn;
#pragma unroll
    for (int ks = 0; ks < 5; ++ks) {
      // issue value-fragment loads; they complete under the gate MFMAs
#pragma unroll
      for (int nt = 0; nt < 10; ++nt)
        bv[nt] = *(const short8*)(wp5 + ((ks * 10 + nt) << 9));
      if (ks < 4) afn = *(const short8*)&L.e[eidx(lr, (ks + 1) * 32 + quad * 8)];
#pragma unroll
      for (int nt = 0; nt < 10; ++nt)
        accg[nt] = __builtin_amdgcn_mfma_f32_16x16x32_bf16(af, bg[nt], accg[nt], 0, 0, 0);
      // issue next gate group; completes under the value MFMAs
#pragma unroll
      for (int nt = 0; nt < 10; ++nt)
        if (ks < 4) bgn[nt] = *(const short8*)(wp4 + (((ks + 1) * 10 + nt) << 9));
#pragma unroll
      for (int nt = 0; nt < 10; ++nt)
        accv[nt] = __builtin_amdgcn_mfma_f32_16x16x32_bf16(af, bv[nt], accv[nt], 0, 0, 0);
#pragma unroll
      for (int nt = 0; nt < 10; ++nt)
        if (ks < 4) bg[nt] = bgn[nt];
      if (ks < 4) af = afn;
    }

    // issue the LN-pass x reload NOW; HBM latency hides under the GLU epilogue
    const int lrow = lane >> 2;
    const int seg  = lane & 3;
    const float* xrp = x + (size_t)(rowbase + lrow) * D + seg * 40;
    f32x4 xv[10];
#pragma unroll
    for (int i = 0; i < 10; ++i) xv[i] = *(const f32x4*)(xrp + i * 4);

#pragma unroll
    for (int nt = 0; nt < 10; ++nt) {
#pragma unroll
      for (int r = 0; r < 4; ++r) {
        float g = accg[nt][r] + bias4[nt];
        float v = accv[nt][r] + bias5[nt];
        L.g[gidx(quad * 4 + r, nt * 16 + lr)] = v * __builtin_amdgcn_rcpf(1.f + __expf(-g));
      }
    }

    // ---------------- LN pass: y = x + glu, normalize, store ----------------
    f32x4 yv[10];
    float sum = 0.f, ssq = 0.f;
#pragma unroll
    for (int i = 0; i < 10; ++i) {
      f32x4 gl = *(const f32x4*)&L.g[gidx(lrow, seg * 40 + i * 4)];
      f32x4 y;
#pragma unroll
      for (int j = 0; j < 4; ++j) {
        y[j] = xv[i][j] + gl[j];
        sum += y[j];
        ssq += y[j] * y[j];
      }
      yv[i] = y;
    }
    sum += __shfl_xor(sum, 1, 64); ssq += __shfl_xor(ssq, 1, 64);
    sum += __shfl_xor(sum, 2, 64); ssq += __shfl_xor(ssq, 2, 64);
    float mean = sum * (1.f / 160.f);
    float var  = ssq * (1.f / 160.f) - mean * mean;
    float rstd = __builtin_amdgcn_rsqf(var + 1e-5f);

    const float* gp = gamma + seg * 40;
    const float* bp = beta  + seg * 40;
    float* op = out + (size_t)(rowbase + lrow) * D + seg * 40;
#pragma unroll
    for (int i = 0; i < 10; ++i) {
      f32x4 ga = *(const f32x4*)(gp + i * 4);
      f32x4 be = *(const f32x4*)(bp + i * 4);
      f32x4 o;
#pragma unroll
      for (int j = 0; j < 4; ++j)
        o[j] = (yv[i][j] - mean) * rstd * ga[j] + be[j];
      *(f32x4*)(op + i * 4) = o;
    }
  }
}

extern "C" void kernel_launch(void* const* d_in, const int* in_sizes, int n_in,
                              void* d_out, int out_size, void* d_ws, size_t ws_size,
                              hipStream_t stream) {
  const float* x     = (const float*)d_in[0];
  const float* c     = (const float*)d_in[1];
  const float* W2    = (const float*)d_in[2];
  const float* b2    = (const float*)d_in[3];
  const float* W3    = (const float*)d_in[4];
  const float* W1    = (const float*)d_in[5];
  const float* b1    = (const float*)d_in[6];
  const float* W4    = (const float*)d_in[7];
  const float* b4    = (const float*)d_in[8];
  const float* W5    = (const float*)d_in[9];
  const float* b5    = (const float*)d_in[10];
  const float* gamma = (const float*)d_in[11];
  const float* beta  = (const float*)d_in[12];

  short* ws = (short*)d_ws;   // 256000 B; re-packed every launch
  prep_kernel<<<500, 256, 0, stream>>>(W2, W3, W1, W4, W5, ws);

  const short* wcatf = ws;
  const short* w1f   = ws + 51200;
  const short* w4f   = w1f + 25600;
  const short* w5f   = w4f + 25600;

  grn_main<<<NTOK / RW, 64, 0, stream>>>(x, c, wcatf, w1f, w4f, w5f,
                                         b2, b1, b4, b5, gamma, beta,
                                         (float*)d_out);
}